// Round 15
// baseline (740.473 us; speedup 1.0000x reference)
//
#include <hip/hip_runtime.h>
#include <hip/hip_bf16.h>

#define DISPL 3
#define NHEADS 6
#define HH 224
#define NB 2
#define MROWS (NB*HH*HH)   // 100352

typedef __attribute__((ext_vector_type(8))) short short8v;
typedef __attribute__((ext_vector_type(4))) float f32x4;

__device__ __forceinline__ float b2f(unsigned short u) {
    unsigned v = ((unsigned)u) << 16;
    return __builtin_bit_cast(float, v);
}
__device__ __forceinline__ unsigned short f2b(float f) {
    unsigned u = __builtin_bit_cast(unsigned, f);
    return (unsigned short)((u + 0x7FFFu + ((u >> 16) & 1u)) >> 16);
}
__device__ __forceinline__ unsigned pack2(float a, float b) {
    return (unsigned)f2b(a) | ((unsigned)f2b(b) << 16);
}
// fast GELU (tanh form, max abs err ~5e-4 vs exact erf form; validated r7-r14)
__device__ __forceinline__ float gelu_f(float x) {
    float y = 0.7978845608028654f * (x + 0.044715f * x * x * x);
    float e = __expf(2.0f * y);
    float th = 1.0f - 2.0f / (1.0f + e);
    return 0.5f * x * (1.0f + th);
}

// regroup: build an MFMA A/B fragment (k = 8*hi + e over a 32-wide k-range)
// from C-frag-layout data (k' = 16*m + 4*hi + r).
__device__ __forceinline__ short8v regroup(unsigned pa0, unsigned pa1,
                                           unsigned pb0, unsigned pb1,
                                           int iq, int hi) {
    int l0 = iq + 16 * (2 * (hi & 1));
    int l1 = l0 + 16;
    int msel = hi >> 1;
    unsigned a0 = (unsigned)__shfl((int)pa0, l0), a1 = (unsigned)__shfl((int)pa1, l0);
    unsigned b0 = (unsigned)__shfl((int)pb0, l0), b1 = (unsigned)__shfl((int)pb1, l0);
    unsigned c0 = (unsigned)__shfl((int)pa0, l1), c1 = (unsigned)__shfl((int)pa1, l1);
    unsigned d0 = (unsigned)__shfl((int)pb0, l1), d1 = (unsigned)__shfl((int)pb1, l1);
    unsigned r0 = msel ? b0 : a0, r1 = msel ? b1 : a1;
    unsigned r2 = msel ? d0 : c0, r3 = msel ? d1 : c1;
    short8v out;
    ((unsigned*)&out)[0] = r0; ((unsigned*)&out)[1] = r1;
    ((unsigned*)&out)[2] = r2; ((unsigned*)&out)[3] = r3;
    return out;
}

// ---------------- fused weight convert+transpose for all 9 weights ----------
struct WtArgs {
    const float* src[9];
    unsigned short* dst[9];
    int K[9];
    int N[9];
};
__global__ __launch_bounds__(256) void wt9_k(WtArgs a) {
    int seg = blockIdx.y;
    int K = a.K[seg], N = a.N[seg];
    int idx = blockIdx.x * 256 + threadIdx.x;
    if (idx >= K * N) return;
    int n = idx % N, k = idx / N;
    a.dst[seg][(size_t)n * K + k] = f2b(a.src[seg][idx]);
}

// =====================================================================
// PatchMerge: fused unfold(x) -> X_lds(bf16) -> GEMM(pm_wt) + bias -> tbuf f32
// =====================================================================
__global__ __launch_bounds__(256, 3) void pm_k(const float* __restrict__ x,
                                               const unsigned short* __restrict__ Bt,
                                               const float* __restrict__ bias,
                                               float* __restrict__ tout) {
    __shared__ unsigned short X[64 * 392];
    int t = threadIdx.x, lane = t & 63, w = t >> 6;
    int iq = lane & 15, hi = lane >> 4;
    int m0 = blockIdx.x * 64;
    int lane16 = t & 15, g = t >> 4;
    int base[4];
    #pragma unroll
    for (int rg = 0; rg < 4; rg++) {
        int m = m0 + 16 * rg + lane16;
        int j = m % 224; int bi = m / 224; int i = bi % 224; int b = bi / 224;
        base[rg] = ((b * 96) * 448 + 2 * i) * 448 + 2 * j;
    }
    for (int step = 0; step < 48; step++) {
        int u = g + 16 * step;
        int rg = u & 3, cp = u >> 2;
        int c = cp >> 1, p1 = cp & 1;
        float2 v = *(const float2*)(x + base[rg] + c * 200704 + p1 * 448);
        *(unsigned*)&X[(16 * rg + lane16) * 392 + c * 4 + p1 * 2] = pack2(v.x, v.y);
    }
    __syncthreads();
    f32x4 acc[4][3] = {};
    #pragma unroll 3
    for (int kk = 0; kk < 12; kk++) {
        short8v a[4], bfr[3];
        #pragma unroll
        for (int mt = 0; mt < 4; mt++)
            a[mt] = *(const short8v*)&X[(16 * mt + iq) * 392 + kk * 32 + hi * 8];
        #pragma unroll
        for (int nt = 0; nt < 3; nt++)
            bfr[nt] = *(const short8v*)&Bt[(size_t)(48 * w + 16 * nt + iq) * 384 + kk * 32 + hi * 8];
        #pragma unroll
        for (int mt = 0; mt < 4; mt++)
            #pragma unroll
            for (int nt = 0; nt < 3; nt++)
                acc[mt][nt] = __builtin_amdgcn_mfma_f32_16x16x32_bf16(a[mt], bfr[nt], acc[mt][nt], 0, 0, 0);
    }
    #pragma unroll
    for (int nt = 0; nt < 3; nt++) {
        int col = 48 * w + 16 * nt + iq;
        float bv = bias[col];
        #pragma unroll
        for (int mt = 0; mt < 4; mt++)
            #pragma unroll
            for (int rr = 0; rr < 4; rr++) {
                size_t row = m0 + 16 * mt + 4 * hi + rr;
                tout[row * 192 + col] = acc[mt][nt][rr] + bv;
            }
    }
}

// =====================================================================
// Fused Swin attention block (r14 proven: AO<->X alias + Bt49 table)
// =====================================================================
template<int SHIFT>
__global__ __launch_bounds__(384, 4) void attn_blk_k(
    const unsigned short* __restrict__ wqkvT, const unsigned short* __restrict__ woT,
    const float* __restrict__ ln1g, const float* __restrict__ ln1b,
    const float* __restrict__ pos, const float* __restrict__ bo,
    float* __restrict__ tbuf)
{
    __shared__ unsigned short X[64 * 200];     // reused as AO after QK pass
    __shared__ unsigned short Vt[6][32 * 72];
    __shared__ float Bt49[49 * 52];
    __shared__ int rtb[64];
    unsigned short* AO = &X[0];

    int t = threadIdx.x, lane = t & 63, wid = t >> 6;
    int iq = lane & 15, hi = lane >> 4;
    int window = blockIdx.x;
    int b = window >> 10, wrem = window & 1023;
    int wi = wrem >> 5, wj = wrem & 31;

    auto trow = [&](int p) -> int {
        int pi = p / 7, pj = p - pi * 7;
        int gi = wi * 7 + pi, gj = wj * 7 + pj;
        if (SHIFT) { gi += DISPL; if (gi >= HH) gi -= HH; gj += DISPL; if (gj >= HH) gj -= HH; }
        return (b * HH + gi) * HH + gj;
    };

    if (t < 49) rtb[t] = trow(t);
    for (int e = t; e < 49 * 49; e += 384) {
        int j = e / 49, i = e - 49 * j;
        int ih = i / 7, iw2 = i - ih * 7;
        int jh = j / 7, jw2 = j - jh * 7;
        float v = pos[(jh - ih + 6) * 13 + (jw2 - iw2 + 6)];
        if (SHIFT) {
            bool msk = false;
            if (wi == 31) msk = msk || ((i >= 28) != (j >= 28));
            if (wj == 31) msk = msk || ((iw2 >= 4) != (jw2 >= 4));
            if (msk) v = -1e30f;
        }
        Bt49[j * 52 + i] = v;
    }
    for (int q = t; q < 1500; q += 384) *(unsigned*)&X[49 * 200 + 2 * q] = 0;

    {
        int c8 = t & 7;
        for (int p = t >> 3; p < 49; p += 48) {
            const float* ar = tbuf + (size_t)trow(p) * 192 + c8 * 24;
            float v[24];
            #pragma unroll
            for (int u8 = 0; u8 < 6; u8++) {
                float4 f = *(const float4*)(ar + u8 * 4);
                v[u8 * 4 + 0] = f.x; v[u8 * 4 + 1] = f.y; v[u8 * 4 + 2] = f.z; v[u8 * 4 + 3] = f.w;
            }
            float s = 0.f, sq = 0.f;
            #pragma unroll
            for (int u = 0; u < 24; u++) { s += v[u]; sq += v[u] * v[u]; }
            s += __shfl_xor(s, 1); s += __shfl_xor(s, 2); s += __shfl_xor(s, 4);
            sq += __shfl_xor(sq, 1); sq += __shfl_xor(sq, 2); sq += __shfl_xor(sq, 4);
            float mean = s * (1.f / 192.f);
            float rstd = rsqrtf(sq * (1.f / 192.f) - mean * mean + 1e-5f);
            unsigned short ov[24];
            #pragma unroll
            for (int u8 = 0; u8 < 6; u8++) {
                float4 gg = *(const float4*)(ln1g + c8 * 24 + u8 * 4);
                float4 bb = *(const float4*)(ln1b + c8 * 24 + u8 * 4);
                ov[u8 * 4 + 0] = f2b((v[u8 * 4 + 0] - mean) * rstd * gg.x + bb.x);
                ov[u8 * 4 + 1] = f2b((v[u8 * 4 + 1] - mean) * rstd * gg.y + bb.y);
                ov[u8 * 4 + 2] = f2b((v[u8 * 4 + 2] - mean) * rstd * gg.z + bb.z);
                ov[u8 * 4 + 3] = f2b((v[u8 * 4 + 3] - mean) * rstd * gg.w + bb.w);
            }
            #pragma unroll
            for (int u = 0; u < 3; u++)
                *(short8v*)&X[p * 200 + c8 * 24 + u * 8] = *(short8v*)&ov[u * 8];
        }
    }
    __syncthreads();

    int hq = wid * 32;
    unsigned short* vt = &Vt[wid][0];

    {
        f32x4 dv[2][4] = {};
        #pragma unroll
        for (int kk = 0; kk < 6; kk++) {
            short8v aw[2], bx[4];
            #pragma unroll
            for (int s2 = 0; s2 < 2; s2++)
                aw[s2] = *(const short8v*)&wqkvT[(size_t)(384 + hq + 16 * s2 + iq) * 192 + kk * 32 + hi * 8];
            #pragma unroll
            for (int tg = 0; tg < 4; tg++)
                bx[tg] = *(const short8v*)&X[(16 * tg + iq) * 200 + kk * 32 + hi * 8];
            #pragma unroll
            for (int s2 = 0; s2 < 2; s2++)
                #pragma unroll
                for (int tg = 0; tg < 4; tg++)
                    dv[s2][tg] = __builtin_amdgcn_mfma_f32_16x16x32_bf16(aw[s2], bx[tg], dv[s2][tg], 0, 0, 0);
        }
        #pragma unroll
        for (int s2 = 0; s2 < 2; s2++)
            #pragma unroll
            for (int tg = 0; tg < 4; tg++)
                #pragma unroll
                for (int rr = 0; rr < 4; rr++)
                    vt[(16 * s2 + 4 * hi + rr) * 72 + 16 * tg + iq] = f2b(dv[s2][tg][rr]);
    }

    short8v bQ[4], aK[4];
    {
        f32x4 dq[2][4] = {}, dk[2][4] = {};
        #pragma unroll
        for (int kk = 0; kk < 6; kk++) {
            short8v aq[2], ak[2], bx[4];
            #pragma unroll
            for (int s2 = 0; s2 < 2; s2++) {
                aq[s2] = *(const short8v*)&wqkvT[(size_t)(hq + 16 * s2 + iq) * 192 + kk * 32 + hi * 8];
                ak[s2] = *(const short8v*)&wqkvT[(size_t)(192 + hq + 16 * s2 + iq) * 192 + kk * 32 + hi * 8];
            }
            #pragma unroll
            for (int tg = 0; tg < 4; tg++)
                bx[tg] = *(const short8v*)&X[(16 * tg + iq) * 200 + kk * 32 + hi * 8];
            #pragma unroll
            for (int s2 = 0; s2 < 2; s2++)
                #pragma unroll
                for (int tg = 0; tg < 4; tg++) {
                    dq[s2][tg] = __builtin_amdgcn_mfma_f32_16x16x32_bf16(aq[s2], bx[tg], dq[s2][tg], 0, 0, 0);
                    dk[s2][tg] = __builtin_amdgcn_mfma_f32_16x16x32_bf16(ak[s2], bx[tg], dk[s2][tg], 0, 0, 0);
                }
        }
        #pragma unroll
        for (int tg = 0; tg < 4; tg++) {
            unsigned q00 = pack2(dq[0][tg][0], dq[0][tg][1]), q01 = pack2(dq[0][tg][2], dq[0][tg][3]);
            unsigned q10 = pack2(dq[1][tg][0], dq[1][tg][1]), q11 = pack2(dq[1][tg][2], dq[1][tg][3]);
            bQ[tg] = regroup(q00, q01, q10, q11, iq, hi);
            unsigned k00 = pack2(dk[0][tg][0], dk[0][tg][1]), k01 = pack2(dk[0][tg][2], dk[0][tg][3]);
            unsigned k10 = pack2(dk[1][tg][0], dk[1][tg][1]), k11 = pack2(dk[1][tg][2], dk[1][tg][3]);
            aK[tg] = regroup(k00, k01, k10, k11, iq, hi);
        }
    }

    f32x4 st[4][4] = {};
    #pragma unroll
    for (int jt = 0; jt < 4; jt++)
        #pragma unroll
        for (int it = 0; it < 4; it++)
            st[jt][it] = __builtin_amdgcn_mfma_f32_16x16x32_bf16(aK[jt], bQ[it], st[jt][it], 0, 0, 0);

    const float scale = 0.17677669529663687f;
    unsigned pkp[4][4][2];
    #pragma unroll
    for (int it = 0; it < 4; it++) {
        int i = iq + 16 * it;
        int icl = i > 48 ? 48 : i;
        float sv[16];
        #pragma unroll
        for (int jt = 0; jt < 4; jt++) {
            #pragma unroll
            for (int r = 0; r < 4; r++) {
                int jj = 16 * jt + 4 * hi + r;
                float s;
                if (jj < 49) s = st[jt][it][r] * scale + Bt49[jj * 52 + icl];
                else s = -1e30f;
                sv[jt * 4 + r] = s;
            }
        }
        float mx = sv[0];
        #pragma unroll
        for (int u = 1; u < 16; u++) mx = fmaxf(mx, sv[u]);
        mx = fmaxf(mx, __shfl_xor(mx, 16));
        mx = fmaxf(mx, __shfl_xor(mx, 32));
        float sum = 0.f;
        #pragma unroll
        for (int u = 0; u < 16; u++) { sv[u] = __expf(sv[u] - mx); sum += sv[u]; }
        sum += __shfl_xor(sum, 16);
        sum += __shfl_xor(sum, 32);
        float rinv = 1.0f / sum;
        #pragma unroll
        for (int jt = 0; jt < 4; jt++) {
            pkp[it][jt][0] = pack2(sv[jt * 4 + 0] * rinv, sv[jt * 4 + 1] * rinv);
            pkp[it][jt][1] = pack2(sv[jt * 4 + 2] * rinv, sv[jt * 4 + 3] * rinv);
        }
    }

    f32x4 o[4][2] = {};
    #pragma unroll
    for (int kk = 0; kk < 2; kk++) {
        short8v bV[2];
        #pragma unroll
        for (int ntv = 0; ntv < 2; ntv++)
            bV[ntv] = *(const short8v*)&vt[(iq + 16 * ntv) * 72 + kk * 32 + hi * 8];
        #pragma unroll
        for (int it = 0; it < 4; it++) {
            short8v aP = regroup(pkp[it][2 * kk][0], pkp[it][2 * kk][1],
                                 pkp[it][2 * kk + 1][0], pkp[it][2 * kk + 1][1], iq, hi);
            o[it][0] = __builtin_amdgcn_mfma_f32_16x16x32_bf16(aP, bV[0], o[it][0], 0, 0, 0);
            o[it][1] = __builtin_amdgcn_mfma_f32_16x16x32_bf16(aP, bV[1], o[it][1], 0, 0, 0);
        }
    }

    __syncthreads();
    #pragma unroll
    for (int it = 0; it < 4; it++)
        #pragma unroll
        for (int ntv = 0; ntv < 2; ntv++)
            #pragma unroll
            for (int rr = 0; rr < 4; rr++)
                AO[(16 * it + 4 * hi + rr) * 200 + hq + 16 * ntv + iq] = f2b(o[it][ntv][rr]);
    __syncthreads();

    f32x4 a2[4][2] = {};
    #pragma unroll
    for (int kk = 0; kk < 6; kk++) {
        short8v aA[4], bW[2];
        #pragma unroll
        for (int mt = 0; mt < 4; mt++)
            aA[mt] = *(const short8v*)&AO[(16 * mt + iq) * 200 + kk * 32 + hi * 8];
        #pragma unroll
        for (int nt = 0; nt < 2; nt++)
            bW[nt] = *(const short8v*)&woT[(size_t)(32 * wid + 16 * nt + iq) * 192 + kk * 32 + hi * 8];
        #pragma unroll
        for (int mt = 0; mt < 4; mt++)
            #pragma unroll
            for (int nt = 0; nt < 2; nt++)
                a2[mt][nt] = __builtin_amdgcn_mfma_f32_16x16x32_bf16(aA[mt], bW[nt], a2[mt][nt], 0, 0, 0);
    }
    #pragma unroll
    for (int nt = 0; nt < 2; nt++) {
        int col = 32 * wid + 16 * nt + iq;
        float bv = bo[col];
        #pragma unroll
        for (int mt = 0; mt < 4; mt++)
            #pragma unroll
            for (int rr = 0; rr < 4; rr++) {
                int i = 16 * mt + 4 * hi + rr;
                if (i < 49) {
                    size_t r = (size_t)rtb[i] * 192 + col;
                    tbuf[r] = a2[mt][nt][rr] + bv + tbuf[r];
                }
            }
    }
}

// =====================================================================
// Fused MLP block v6 + TO: TO=0 writes tbuf in place (s=0);
// TO=1 writes d_out directly in [b][c][i][j] layout (s=1, tr_k fused).
// float4 packing valid: 224%4==0 and row-base%4==0 => 4 consecutive
// rows share one (b,c,i) and give consecutive j.
// =====================================================================
template<int TO>
__global__ __launch_bounds__(256, 3) void mlp_k(const unsigned short* __restrict__ w1T,
                                                const unsigned short* __restrict__ w2T,
                                                const float* __restrict__ ln2g,
                                                const float* __restrict__ ln2b,
                                                const float* __restrict__ b1,
                                                const float* __restrict__ b2,
                                                float* __restrict__ tbuf,
                                                float* __restrict__ outp)
{
    __shared__ unsigned short X[64 * 200];
    __shared__ unsigned short Hl[64 * 200];
    int t = threadIdx.x, lane = t & 63, w = t >> 6;
    int iq = lane & 15, hi = lane >> 4;
    int m0 = blockIdx.x * 64;

    {
        int c8 = t & 7, p0 = t >> 3;
        #pragma unroll
        for (int pp = 0; pp < 2; pp++) {
            int p = p0 + 32 * pp;
            const float* ar = tbuf + (size_t)(m0 + p) * 192 + c8 * 24;
            float v[24];
            #pragma unroll
            for (int u8 = 0; u8 < 6; u8++) {
                float4 f = *(const float4*)(ar + u8 * 4);
                v[u8 * 4 + 0] = f.x; v[u8 * 4 + 1] = f.y; v[u8 * 4 + 2] = f.z; v[u8 * 4 + 3] = f.w;
            }
            float s = 0.f, sq = 0.f;
            #pragma unroll
            for (int u = 0; u < 24; u++) { s += v[u]; sq += v[u] * v[u]; }
            s += __shfl_xor(s, 1); s += __shfl_xor(s, 2); s += __shfl_xor(s, 4);
            sq += __shfl_xor(sq, 1); sq += __shfl_xor(sq, 2); sq += __shfl_xor(sq, 4);
            float mean = s * (1.f / 192.f);
            float rstd = rsqrtf(sq * (1.f / 192.f) - mean * mean + 1e-5f);
            unsigned short ov[24];
            #pragma unroll
            for (int u8 = 0; u8 < 6; u8++) {
                float4 gg = *(const float4*)(ln2g + c8 * 24 + u8 * 4);
                float4 bb = *(const float4*)(ln2b + c8 * 24 + u8 * 4);
                ov[u8 * 4 + 0] = f2b((v[u8 * 4 + 0] - mean) * rstd * gg.x + bb.x);
                ov[u8 * 4 + 1] = f2b((v[u8 * 4 + 1] - mean) * rstd * gg.y + bb.y);
                ov[u8 * 4 + 2] = f2b((v[u8 * 4 + 2] - mean) * rstd * gg.z + bb.z);
                ov[u8 * 4 + 3] = f2b((v[u8 * 4 + 3] - mean) * rstd * gg.w + bb.w);
            }
            #pragma unroll
            for (int u = 0; u < 3; u++)
                *(short8v*)&X[p * 200 + c8 * 24 + u * 8] = *(short8v*)&ov[u * 8];
        }
    }
    __syncthreads();

    f32x4 acc2[4][3] = {};
    #pragma unroll 1
    for (int c = 0; c < 4; c++) {
        f32x4 acc1[4][3] = {};
        #pragma unroll
        for (int kk = 0; kk < 6; kk++) {
            short8v aX[4], bW[3];
            #pragma unroll
            for (int mt = 0; mt < 4; mt++)
                aX[mt] = *(const short8v*)&X[(16 * mt + iq) * 200 + kk * 32 + hi * 8];
            #pragma unroll
            for (int nt = 0; nt < 3; nt++)
                bW[nt] = *(const short8v*)&w1T[(size_t)(c * 192 + 48 * w + 16 * nt + iq) * 192 + kk * 32 + hi * 8];
            #pragma unroll
            for (int mt = 0; mt < 4; mt++)
                #pragma unroll
                for (int nt = 0; nt < 3; nt++)
                    acc1[mt][nt] = __builtin_amdgcn_mfma_f32_16x16x32_bf16(aX[mt], bW[nt], acc1[mt][nt], 0, 0, 0);
        }
        #pragma unroll
        for (int nt = 0; nt < 3; nt++) {
            int col = 48 * w + 16 * nt + iq;
            float bv = b1[c * 192 + col];
            #pragma unroll
            for (int mt = 0; mt < 4; mt++)
                #pragma unroll
                for (int rr = 0; rr < 4; rr++)
                    Hl[(16 * mt + 4 * hi + rr) * 200 + col] = f2b(gelu_f(acc1[mt][nt][rr] + bv));
        }
        __syncthreads();
        #pragma unroll
        for (int kk = 0; kk < 6; kk++) {
            short8v aH[4], bW[3];
            #pragma unroll
            for (int mt = 0; mt < 4; mt++)
                aH[mt] = *(const short8v*)&Hl[(16 * mt + iq) * 200 + kk * 32 + hi * 8];
            #pragma unroll
            for (int nt = 0; nt < 3; nt++)
                bW[nt] = *(const short8v*)&w2T[(size_t)(48 * w + 16 * nt + iq) * 768 + c * 192 + kk * 32 + hi * 8];
            #pragma unroll
            for (int mt = 0; mt < 4; mt++)
                #pragma unroll
                for (int nt = 0; nt < 3; nt++)
                    acc2[mt][nt] = __builtin_amdgcn_mfma_f32_16x16x32_bf16(aH[mt], bW[nt], acc2[mt][nt], 0, 0, 0);
        }
        __syncthreads();
    }
    if (TO == 0) {
        #pragma unroll
        for (int nt = 0; nt < 3; nt++) {
            int col = 48 * w + 16 * nt + iq;
            float bv = b2[col];
            #pragma unroll
            for (int mt = 0; mt < 4; mt++)
                #pragma unroll
                for (int rr = 0; rr < 4; rr++) {
                    size_t r = (size_t)(m0 + 16 * mt + 4 * hi + rr) * 192 + col;
                    tbuf[r] = acc2[mt][nt][rr] + bv + tbuf[r];
                }
        }
    } else {
        // fused transpose-out: row = (b*224+i)*224+j -> out[((b*192+col)*224+i)*224+j]
        #pragma unroll
        for (int mt = 0; mt < 4; mt++) {
            int rowb = m0 + 16 * mt + 4 * hi;
            int j = rowb % 224;
            int bi2 = rowb / 224;
            int ii = bi2 % 224;
            int bb = bi2 / 224;
            #pragma unroll
            for (int nt = 0; nt < 3; nt++) {
                int col = 48 * w + 16 * nt + iq;
                float bv = b2[col];
                float4 vv;
                vv.x = acc2[mt][nt][0] + bv + tbuf[(size_t)(rowb + 0) * 192 + col];
                vv.y = acc2[mt][nt][1] + bv + tbuf[(size_t)(rowb + 1) * 192 + col];
                vv.z = acc2[mt][nt][2] + bv + tbuf[(size_t)(rowb + 2) * 192 + col];
                vv.w = acc2[mt][nt][3] + bv + tbuf[(size_t)(rowb + 3) * 192 + col];
                *(float4*)&outp[(((size_t)bb * 192 + col) * 224 + ii) * 224 + j] = vv;
            }
        }
    }
}

extern "C" void kernel_launch(void* const* d_in, const int* in_sizes, int n_in,
                              void* d_out, int out_size, void* d_ws, size_t ws_size,
                              hipStream_t stream) {
    (void)in_sizes; (void)n_in; (void)out_size; (void)ws_size;
    const float* x    = (const float*)d_in[0];
    const float* pm_w = (const float*)d_in[1];
    const float* pm_b = (const float*)d_in[2];

    char* ws = (char*)d_ws;
    size_t off = 0;
    float* tbuf = (float*)(ws + off); off += (size_t)MROWS * 192 * 4;
    unsigned short* pm_wt = (unsigned short*)(ws + off); off += 192 * 384 * 2;
    unsigned short* wqkv_t[2]; unsigned short* wo_t[2];
    unsigned short* w1_t[2];   unsigned short* w2_t[2];
    for (int s = 0; s < 2; s++) {
        wqkv_t[s] = (unsigned short*)(ws + off); off += 576 * 192 * 2;
        wo_t[s]   = (unsigned short*)(ws + off); off += 192 * 192 * 2;
        w1_t[s]   = (unsigned short*)(ws + off); off += 768 * 192 * 2;
        w2_t[s]   = (unsigned short*)(ws + off); off += 192 * 768 * 2;
    }

    WtArgs wa;
    wa.src[0] = pm_w; wa.dst[0] = pm_wt; wa.K[0] = 384; wa.N[0] = 192;
    for (int s = 0; s < 2; s++) {
        wa.src[1 + 4 * s] = (const float*)d_in[5 + 12 * s];  wa.dst[1 + 4 * s] = wqkv_t[s]; wa.K[1 + 4 * s] = 192; wa.N[1 + 4 * s] = 576;
        wa.src[2 + 4 * s] = (const float*)d_in[7 + 12 * s];  wa.dst[2 + 4 * s] = wo_t[s];   wa.K[2 + 4 * s] = 192; wa.N[2 + 4 * s] = 192;
        wa.src[3 + 4 * s] = (const float*)d_in[11 + 12 * s]; wa.dst[3 + 4 * s] = w1_t[s];   wa.K[3 + 4 * s] = 192; wa.N[3 + 4 * s] = 768;
        wa.src[4 + 4 * s] = (const float*)d_in[13 + 12 * s]; wa.dst[4 + 4 * s] = w2_t[s];   wa.K[4 + 4 * s] = 768; wa.N[4 + 4 * s] = 192;
    }
    wt9_k<<<dim3(576, 9), 256, 0, stream>>>(wa);

    pm_k<<<MROWS / 64, 256, 0, stream>>>(x, pm_wt, pm_b, tbuf);

    for (int s = 0; s < 2; s++) {
        const float* ln1g = (const float*)d_in[3 + 12 * s];
        const float* ln1b = (const float*)d_in[4 + 12 * s];
        const float* pos  = (const float*)d_in[6 + 12 * s];
        const float* bo   = (const float*)d_in[8 + 12 * s];
        const float* ln2g = (const float*)d_in[9 + 12 * s];
        const float* ln2b = (const float*)d_in[10 + 12 * s];
        const float* b1   = (const float*)d_in[12 + 12 * s];
        const float* b2   = (const float*)d_in[14 + 12 * s];

        if (s == 0) {
            attn_blk_k<0><<<2048, 384, 0, stream>>>(wqkv_t[0], wo_t[0], ln1g, ln1b, pos, bo, tbuf);
            mlp_k<0><<<MROWS / 64, 256, 0, stream>>>(w1_t[0], w2_t[0], ln2g, ln2b, b1, b2, tbuf, nullptr);
        } else {
            attn_blk_k<1><<<2048, 384, 0, stream>>>(wqkv_t[1], wo_t[1], ln1g, ln1b, pos, bo, tbuf);
            mlp_k<1><<<MROWS / 64, 256, 0, stream>>>(w1_t[1], w2_t[1], ln2g, ln2b, b1, b2, tbuf, (float*)d_out);
        }
    }
}

// Round 16
// 723.277 us; speedup vs baseline: 1.0238x; 1.0238x over previous
//
#include <hip/hip_runtime.h>
#include <hip/hip_bf16.h>

#define DISPL 3
#define NHEADS 6
#define HH 224
#define NB 2
#define MROWS (NB*HH*HH)   // 100352

typedef __attribute__((ext_vector_type(8))) short short8v;
typedef __attribute__((ext_vector_type(4))) float f32x4;

__device__ __forceinline__ float b2f(unsigned short u) {
    unsigned v = ((unsigned)u) << 16;
    return __builtin_bit_cast(float, v);
}
__device__ __forceinline__ unsigned short f2b(float f) {
    unsigned u = __builtin_bit_cast(unsigned, f);
    return (unsigned short)((u + 0x7FFFu + ((u >> 16) & 1u)) >> 16);
}
__device__ __forceinline__ unsigned pack2(float a, float b) {
    return (unsigned)f2b(a) | ((unsigned)f2b(b) << 16);
}
// sigmoid-form GELU: x*sigmoid(1.702x), ~6 VALU ops (max abs err ~0.01,
// attenuated ~0.02*sqrt(768) through w2 => ~0.006-0.01 on output)
__device__ __forceinline__ float gelu_f(float x) {
    return x / (1.0f + __expf(-1.702f * x));
}

// regroup: build an MFMA A/B fragment (k = 8*hi + e over a 32-wide k-range)
// from C-frag-layout data (k' = 16*m + 4*hi + r).
__device__ __forceinline__ short8v regroup(unsigned pa0, unsigned pa1,
                                           unsigned pb0, unsigned pb1,
                                           int iq, int hi) {
    int l0 = iq + 16 * (2 * (hi & 1));
    int l1 = l0 + 16;
    int msel = hi >> 1;
    unsigned a0 = (unsigned)__shfl((int)pa0, l0), a1 = (unsigned)__shfl((int)pa1, l0);
    unsigned b0 = (unsigned)__shfl((int)pb0, l0), b1 = (unsigned)__shfl((int)pb1, l0);
    unsigned c0 = (unsigned)__shfl((int)pa0, l1), c1 = (unsigned)__shfl((int)pa1, l1);
    unsigned d0 = (unsigned)__shfl((int)pb0, l1), d1 = (unsigned)__shfl((int)pb1, l1);
    unsigned r0 = msel ? b0 : a0, r1 = msel ? b1 : a1;
    unsigned r2 = msel ? d0 : c0, r3 = msel ? d1 : c1;
    short8v out;
    ((unsigned*)&out)[0] = r0; ((unsigned*)&out)[1] = r1;
    ((unsigned*)&out)[2] = r2; ((unsigned*)&out)[3] = r3;
    return out;
}

// ---------------- fused weight convert+transpose for all 9 weights ----------
struct WtArgs {
    const float* src[9];
    unsigned short* dst[9];
    int K[9];
    int N[9];
};
__global__ __launch_bounds__(256) void wt9_k(WtArgs a) {
    int seg = blockIdx.y;
    int K = a.K[seg], N = a.N[seg];
    int idx = blockIdx.x * 256 + threadIdx.x;
    if (idx >= K * N) return;
    int n = idx % N, k = idx / N;
    a.dst[seg][(size_t)n * K + k] = f2b(a.src[seg][idx]);
}

// =====================================================================
// PatchMerge: fused unfold(x) -> X_lds(bf16) -> GEMM(pm_wt) + bias -> tbuf f32
// =====================================================================
__global__ __launch_bounds__(256, 3) void pm_k(const float* __restrict__ x,
                                               const unsigned short* __restrict__ Bt,
                                               const float* __restrict__ bias,
                                               float* __restrict__ tout) {
    __shared__ unsigned short X[64 * 392];
    int t = threadIdx.x, lane = t & 63, w = t >> 6;
    int iq = lane & 15, hi = lane >> 4;
    int m0 = blockIdx.x * 64;
    int lane16 = t & 15, g = t >> 4;
    int base[4];
    #pragma unroll
    for (int rg = 0; rg < 4; rg++) {
        int m = m0 + 16 * rg + lane16;
        int j = m % 224; int bi = m / 224; int i = bi % 224; int b = bi / 224;
        base[rg] = ((b * 96) * 448 + 2 * i) * 448 + 2 * j;
    }
    for (int step = 0; step < 48; step++) {
        int u = g + 16 * step;
        int rg = u & 3, cp = u >> 2;
        int c = cp >> 1, p1 = cp & 1;
        float2 v = *(const float2*)(x + base[rg] + c * 200704 + p1 * 448);
        *(unsigned*)&X[(16 * rg + lane16) * 392 + c * 4 + p1 * 2] = pack2(v.x, v.y);
    }
    __syncthreads();
    f32x4 acc[4][3] = {};
    #pragma unroll 3
    for (int kk = 0; kk < 12; kk++) {
        short8v a[4], bfr[3];
        #pragma unroll
        for (int mt = 0; mt < 4; mt++)
            a[mt] = *(const short8v*)&X[(16 * mt + iq) * 392 + kk * 32 + hi * 8];
        #pragma unroll
        for (int nt = 0; nt < 3; nt++)
            bfr[nt] = *(const short8v*)&Bt[(size_t)(48 * w + 16 * nt + iq) * 384 + kk * 32 + hi * 8];
        #pragma unroll
        for (int mt = 0; mt < 4; mt++)
            #pragma unroll
            for (int nt = 0; nt < 3; nt++)
                acc[mt][nt] = __builtin_amdgcn_mfma_f32_16x16x32_bf16(a[mt], bfr[nt], acc[mt][nt], 0, 0, 0);
    }
    #pragma unroll
    for (int nt = 0; nt < 3; nt++) {
        int col = 48 * w + 16 * nt + iq;
        float bv = bias[col];
        #pragma unroll
        for (int mt = 0; mt < 4; mt++)
            #pragma unroll
            for (int rr = 0; rr < 4; rr++) {
                size_t row = m0 + 16 * mt + 4 * hi + rr;
                tout[row * 192 + col] = acc[mt][nt][rr] + bv;
            }
    }
}

// =====================================================================
// Fused Swin attention block (r14 proven: AO<->X alias + Bt49 table)
// =====================================================================
template<int SHIFT>
__global__ __launch_bounds__(384, 4) void attn_blk_k(
    const unsigned short* __restrict__ wqkvT, const unsigned short* __restrict__ woT,
    const float* __restrict__ ln1g, const float* __restrict__ ln1b,
    const float* __restrict__ pos, const float* __restrict__ bo,
    float* __restrict__ tbuf)
{
    __shared__ unsigned short X[64 * 200];     // reused as AO after QK pass
    __shared__ unsigned short Vt[6][32 * 72];
    __shared__ float Bt49[49 * 52];
    __shared__ int rtb[64];
    unsigned short* AO = &X[0];

    int t = threadIdx.x, lane = t & 63, wid = t >> 6;
    int iq = lane & 15, hi = lane >> 4;
    int window = blockIdx.x;
    int b = window >> 10, wrem = window & 1023;
    int wi = wrem >> 5, wj = wrem & 31;

    auto trow = [&](int p) -> int {
        int pi = p / 7, pj = p - pi * 7;
        int gi = wi * 7 + pi, gj = wj * 7 + pj;
        if (SHIFT) { gi += DISPL; if (gi >= HH) gi -= HH; gj += DISPL; if (gj >= HH) gj -= HH; }
        return (b * HH + gi) * HH + gj;
    };

    if (t < 49) rtb[t] = trow(t);
    for (int e = t; e < 49 * 49; e += 384) {
        int j = e / 49, i = e - 49 * j;
        int ih = i / 7, iw2 = i - ih * 7;
        int jh = j / 7, jw2 = j - jh * 7;
        float v = pos[(jh - ih + 6) * 13 + (jw2 - iw2 + 6)];
        if (SHIFT) {
            bool msk = false;
            if (wi == 31) msk = msk || ((i >= 28) != (j >= 28));
            if (wj == 31) msk = msk || ((iw2 >= 4) != (jw2 >= 4));
            if (msk) v = -1e30f;
        }
        Bt49[j * 52 + i] = v;
    }
    for (int q = t; q < 1500; q += 384) *(unsigned*)&X[49 * 200 + 2 * q] = 0;

    {
        int c8 = t & 7;
        for (int p = t >> 3; p < 49; p += 48) {
            const float* ar = tbuf + (size_t)trow(p) * 192 + c8 * 24;
            float v[24];
            #pragma unroll
            for (int u8 = 0; u8 < 6; u8++) {
                float4 f = *(const float4*)(ar + u8 * 4);
                v[u8 * 4 + 0] = f.x; v[u8 * 4 + 1] = f.y; v[u8 * 4 + 2] = f.z; v[u8 * 4 + 3] = f.w;
            }
            float s = 0.f, sq = 0.f;
            #pragma unroll
            for (int u = 0; u < 24; u++) { s += v[u]; sq += v[u] * v[u]; }
            s += __shfl_xor(s, 1); s += __shfl_xor(s, 2); s += __shfl_xor(s, 4);
            sq += __shfl_xor(sq, 1); sq += __shfl_xor(sq, 2); sq += __shfl_xor(sq, 4);
            float mean = s * (1.f / 192.f);
            float rstd = rsqrtf(sq * (1.f / 192.f) - mean * mean + 1e-5f);
            unsigned short ov[24];
            #pragma unroll
            for (int u8 = 0; u8 < 6; u8++) {
                float4 gg = *(const float4*)(ln1g + c8 * 24 + u8 * 4);
                float4 bb = *(const float4*)(ln1b + c8 * 24 + u8 * 4);
                ov[u8 * 4 + 0] = f2b((v[u8 * 4 + 0] - mean) * rstd * gg.x + bb.x);
                ov[u8 * 4 + 1] = f2b((v[u8 * 4 + 1] - mean) * rstd * gg.y + bb.y);
                ov[u8 * 4 + 2] = f2b((v[u8 * 4 + 2] - mean) * rstd * gg.z + bb.z);
                ov[u8 * 4 + 3] = f2b((v[u8 * 4 + 3] - mean) * rstd * gg.w + bb.w);
            }
            #pragma unroll
            for (int u = 0; u < 3; u++)
                *(short8v*)&X[p * 200 + c8 * 24 + u * 8] = *(short8v*)&ov[u * 8];
        }
    }
    __syncthreads();

    int hq = wid * 32;
    unsigned short* vt = &Vt[wid][0];

    {
        f32x4 dv[2][4] = {};
        #pragma unroll
        for (int kk = 0; kk < 6; kk++) {
            short8v aw[2], bx[4];
            #pragma unroll
            for (int s2 = 0; s2 < 2; s2++)
                aw[s2] = *(const short8v*)&wqkvT[(size_t)(384 + hq + 16 * s2 + iq) * 192 + kk * 32 + hi * 8];
            #pragma unroll
            for (int tg = 0; tg < 4; tg++)
                bx[tg] = *(const short8v*)&X[(16 * tg + iq) * 200 + kk * 32 + hi * 8];
            #pragma unroll
            for (int s2 = 0; s2 < 2; s2++)
                #pragma unroll
                for (int tg = 0; tg < 4; tg++)
                    dv[s2][tg] = __builtin_amdgcn_mfma_f32_16x16x32_bf16(aw[s2], bx[tg], dv[s2][tg], 0, 0, 0);
        }
        #pragma unroll
        for (int s2 = 0; s2 < 2; s2++)
            #pragma unroll
            for (int tg = 0; tg < 4; tg++)
                #pragma unroll
                for (int rr = 0; rr < 4; rr++)
                    vt[(16 * s2 + 4 * hi + rr) * 72 + 16 * tg + iq] = f2b(dv[s2][tg][rr]);
    }

    short8v bQ[4], aK[4];
    {
        f32x4 dq[2][4] = {}, dk[2][4] = {};
        #pragma unroll
        for (int kk = 0; kk < 6; kk++) {
            short8v aq[2], ak[2], bx[4];
            #pragma unroll
            for (int s2 = 0; s2 < 2; s2++) {
                aq[s2] = *(const short8v*)&wqkvT[(size_t)(hq + 16 * s2 + iq) * 192 + kk * 32 + hi * 8];
                ak[s2] = *(const short8v*)&wqkvT[(size_t)(192 + hq + 16 * s2 + iq) * 192 + kk * 32 + hi * 8];
            }
            #pragma unroll
            for (int tg = 0; tg < 4; tg++)
                bx[tg] = *(const short8v*)&X[(16 * tg + iq) * 200 + kk * 32 + hi * 8];
            #pragma unroll
            for (int s2 = 0; s2 < 2; s2++)
                #pragma unroll
                for (int tg = 0; tg < 4; tg++) {
                    dq[s2][tg] = __builtin_amdgcn_mfma_f32_16x16x32_bf16(aq[s2], bx[tg], dq[s2][tg], 0, 0, 0);
                    dk[s2][tg] = __builtin_amdgcn_mfma_f32_16x16x32_bf16(ak[s2], bx[tg], dk[s2][tg], 0, 0, 0);
                }
        }
        #pragma unroll
        for (int tg = 0; tg < 4; tg++) {
            unsigned q00 = pack2(dq[0][tg][0], dq[0][tg][1]), q01 = pack2(dq[0][tg][2], dq[0][tg][3]);
            unsigned q10 = pack2(dq[1][tg][0], dq[1][tg][1]), q11 = pack2(dq[1][tg][2], dq[1][tg][3]);
            bQ[tg] = regroup(q00, q01, q10, q11, iq, hi);
            unsigned k00 = pack2(dk[0][tg][0], dk[0][tg][1]), k01 = pack2(dk[0][tg][2], dk[0][tg][3]);
            unsigned k10 = pack2(dk[1][tg][0], dk[1][tg][1]), k11 = pack2(dk[1][tg][2], dk[1][tg][3]);
            aK[tg] = regroup(k00, k01, k10, k11, iq, hi);
        }
    }

    f32x4 st[4][4] = {};
    #pragma unroll
    for (int jt = 0; jt < 4; jt++)
        #pragma unroll
        for (int it = 0; it < 4; it++)
            st[jt][it] = __builtin_amdgcn_mfma_f32_16x16x32_bf16(aK[jt], bQ[it], st[jt][it], 0, 0, 0);

    const float scale = 0.17677669529663687f;
    unsigned pkp[4][4][2];
    #pragma unroll
    for (int it = 0; it < 4; it++) {
        int i = iq + 16 * it;
        int icl = i > 48 ? 48 : i;
        float sv[16];
        #pragma unroll
        for (int jt = 0; jt < 4; jt++) {
            #pragma unroll
            for (int r = 0; r < 4; r++) {
                int jj = 16 * jt + 4 * hi + r;
                float s;
                if (jj < 49) s = st[jt][it][r] * scale + Bt49[jj * 52 + icl];
                else s = -1e30f;
                sv[jt * 4 + r] = s;
            }
        }
        float mx = sv[0];
        #pragma unroll
        for (int u = 1; u < 16; u++) mx = fmaxf(mx, sv[u]);
        mx = fmaxf(mx, __shfl_xor(mx, 16));
        mx = fmaxf(mx, __shfl_xor(mx, 32));
        float sum = 0.f;
        #pragma unroll
        for (int u = 0; u < 16; u++) { sv[u] = __expf(sv[u] - mx); sum += sv[u]; }
        sum += __shfl_xor(sum, 16);
        sum += __shfl_xor(sum, 32);
        float rinv = 1.0f / sum;
        #pragma unroll
        for (int jt = 0; jt < 4; jt++) {
            pkp[it][jt][0] = pack2(sv[jt * 4 + 0] * rinv, sv[jt * 4 + 1] * rinv);
            pkp[it][jt][1] = pack2(sv[jt * 4 + 2] * rinv, sv[jt * 4 + 3] * rinv);
        }
    }

    f32x4 o[4][2] = {};
    #pragma unroll
    for (int kk = 0; kk < 2; kk++) {
        short8v bV[2];
        #pragma unroll
        for (int ntv = 0; ntv < 2; ntv++)
            bV[ntv] = *(const short8v*)&vt[(iq + 16 * ntv) * 72 + kk * 32 + hi * 8];
        #pragma unroll
        for (int it = 0; it < 4; it++) {
            short8v aP = regroup(pkp[it][2 * kk][0], pkp[it][2 * kk][1],
                                 pkp[it][2 * kk + 1][0], pkp[it][2 * kk + 1][1], iq, hi);
            o[it][0] = __builtin_amdgcn_mfma_f32_16x16x32_bf16(aP, bV[0], o[it][0], 0, 0, 0);
            o[it][1] = __builtin_amdgcn_mfma_f32_16x16x32_bf16(aP, bV[1], o[it][1], 0, 0, 0);
        }
    }

    __syncthreads();
    #pragma unroll
    for (int it = 0; it < 4; it++)
        #pragma unroll
        for (int ntv = 0; ntv < 2; ntv++)
            #pragma unroll
            for (int rr = 0; rr < 4; rr++)
                AO[(16 * it + 4 * hi + rr) * 200 + hq + 16 * ntv + iq] = f2b(o[it][ntv][rr]);
    __syncthreads();

    f32x4 a2[4][2] = {};
    #pragma unroll
    for (int kk = 0; kk < 6; kk++) {
        short8v aA[4], bW[2];
        #pragma unroll
        for (int mt = 0; mt < 4; mt++)
            aA[mt] = *(const short8v*)&AO[(16 * mt + iq) * 200 + kk * 32 + hi * 8];
        #pragma unroll
        for (int nt = 0; nt < 2; nt++)
            bW[nt] = *(const short8v*)&woT[(size_t)(32 * wid + 16 * nt + iq) * 192 + kk * 32 + hi * 8];
        #pragma unroll
        for (int mt = 0; mt < 4; mt++)
            #pragma unroll
            for (int nt = 0; nt < 2; nt++)
                a2[mt][nt] = __builtin_amdgcn_mfma_f32_16x16x32_bf16(aA[mt], bW[nt], a2[mt][nt], 0, 0, 0);
    }
    #pragma unroll
    for (int nt = 0; nt < 2; nt++) {
        int col = 32 * wid + 16 * nt + iq;
        float bv = bo[col];
        #pragma unroll
        for (int mt = 0; mt < 4; mt++)
            #pragma unroll
            for (int rr = 0; rr < 4; rr++) {
                int i = 16 * mt + 4 * hi + rr;
                if (i < 49) {
                    size_t r = (size_t)rtb[i] * 192 + col;
                    tbuf[r] = a2[mt][nt][rr] + bv + tbuf[r];
                }
            }
    }
}

// =====================================================================
// Fused MLP block v6 + TO (r15): TO=0 -> tbuf in place; TO=1 -> d_out
// directly in [b][c][i][j] layout (tr_k fused). sigmoid-GELU (r16).
// =====================================================================
template<int TO>
__global__ __launch_bounds__(256, 3) void mlp_k(const unsigned short* __restrict__ w1T,
                                                const unsigned short* __restrict__ w2T,
                                                const float* __restrict__ ln2g,
                                                const float* __restrict__ ln2b,
                                                const float* __restrict__ b1,
                                                const float* __restrict__ b2,
                                                float* __restrict__ tbuf,
                                                float* __restrict__ outp)
{
    __shared__ unsigned short X[64 * 200];
    __shared__ unsigned short Hl[64 * 200];
    int t = threadIdx.x, lane = t & 63, w = t >> 6;
    int iq = lane & 15, hi = lane >> 4;
    int m0 = blockIdx.x * 64;

    {
        int c8 = t & 7, p0 = t >> 3;
        #pragma unroll
        for (int pp = 0; pp < 2; pp++) {
            int p = p0 + 32 * pp;
            const float* ar = tbuf + (size_t)(m0 + p) * 192 + c8 * 24;
            float v[24];
            #pragma unroll
            for (int u8 = 0; u8 < 6; u8++) {
                float4 f = *(const float4*)(ar + u8 * 4);
                v[u8 * 4 + 0] = f.x; v[u8 * 4 + 1] = f.y; v[u8 * 4 + 2] = f.z; v[u8 * 4 + 3] = f.w;
            }
            float s = 0.f, sq = 0.f;
            #pragma unroll
            for (int u = 0; u < 24; u++) { s += v[u]; sq += v[u] * v[u]; }
            s += __shfl_xor(s, 1); s += __shfl_xor(s, 2); s += __shfl_xor(s, 4);
            sq += __shfl_xor(sq, 1); sq += __shfl_xor(sq, 2); sq += __shfl_xor(sq, 4);
            float mean = s * (1.f / 192.f);
            float rstd = rsqrtf(sq * (1.f / 192.f) - mean * mean + 1e-5f);
            unsigned short ov[24];
            #pragma unroll
            for (int u8 = 0; u8 < 6; u8++) {
                float4 gg = *(const float4*)(ln2g + c8 * 24 + u8 * 4);
                float4 bb = *(const float4*)(ln2b + c8 * 24 + u8 * 4);
                ov[u8 * 4 + 0] = f2b((v[u8 * 4 + 0] - mean) * rstd * gg.x + bb.x);
                ov[u8 * 4 + 1] = f2b((v[u8 * 4 + 1] - mean) * rstd * gg.y + bb.y);
                ov[u8 * 4 + 2] = f2b((v[u8 * 4 + 2] - mean) * rstd * gg.z + bb.z);
                ov[u8 * 4 + 3] = f2b((v[u8 * 4 + 3] - mean) * rstd * gg.w + bb.w);
            }
            #pragma unroll
            for (int u = 0; u < 3; u++)
                *(short8v*)&X[p * 200 + c8 * 24 + u * 8] = *(short8v*)&ov[u * 8];
        }
    }
    __syncthreads();

    f32x4 acc2[4][3] = {};
    #pragma unroll 1
    for (int c = 0; c < 4; c++) {
        f32x4 acc1[4][3] = {};
        #pragma unroll
        for (int kk = 0; kk < 6; kk++) {
            short8v aX[4], bW[3];
            #pragma unroll
            for (int mt = 0; mt < 4; mt++)
                aX[mt] = *(const short8v*)&X[(16 * mt + iq) * 200 + kk * 32 + hi * 8];
            #pragma unroll
            for (int nt = 0; nt < 3; nt++)
                bW[nt] = *(const short8v*)&w1T[(size_t)(c * 192 + 48 * w + 16 * nt + iq) * 192 + kk * 32 + hi * 8];
            #pragma unroll
            for (int mt = 0; mt < 4; mt++)
                #pragma unroll
                for (int nt = 0; nt < 3; nt++)
                    acc1[mt][nt] = __builtin_amdgcn_mfma_f32_16x16x32_bf16(aX[mt], bW[nt], acc1[mt][nt], 0, 0, 0);
        }
        #pragma unroll
        for (int nt = 0; nt < 3; nt++) {
            int col = 48 * w + 16 * nt + iq;
            float bv = b1[c * 192 + col];
            #pragma unroll
            for (int mt = 0; mt < 4; mt++)
                #pragma unroll
                for (int rr = 0; rr < 4; rr++)
                    Hl[(16 * mt + 4 * hi + rr) * 200 + col] = f2b(gelu_f(acc1[mt][nt][rr] + bv));
        }
        __syncthreads();
        #pragma unroll
        for (int kk = 0; kk < 6; kk++) {
            short8v aH[4], bW[3];
            #pragma unroll
            for (int mt = 0; mt < 4; mt++)
                aH[mt] = *(const short8v*)&Hl[(16 * mt + iq) * 200 + kk * 32 + hi * 8];
            #pragma unroll
            for (int nt = 0; nt < 3; nt++)
                bW[nt] = *(const short8v*)&w2T[(size_t)(48 * w + 16 * nt + iq) * 768 + c * 192 + kk * 32 + hi * 8];
            #pragma unroll
            for (int mt = 0; mt < 4; mt++)
                #pragma unroll
                for (int nt = 0; nt < 3; nt++)
                    acc2[mt][nt] = __builtin_amdgcn_mfma_f32_16x16x32_bf16(aH[mt], bW[nt], acc2[mt][nt], 0, 0, 0);
        }
        __syncthreads();
    }
    if (TO == 0) {
        #pragma unroll
        for (int nt = 0; nt < 3; nt++) {
            int col = 48 * w + 16 * nt + iq;
            float bv = b2[col];
            #pragma unroll
            for (int mt = 0; mt < 4; mt++)
                #pragma unroll
                for (int rr = 0; rr < 4; rr++) {
                    size_t r = (size_t)(m0 + 16 * mt + 4 * hi + rr) * 192 + col;
                    tbuf[r] = acc2[mt][nt][rr] + bv + tbuf[r];
                }
        }
    } else {
        #pragma unroll
        for (int mt = 0; mt < 4; mt++) {
            int rowb = m0 + 16 * mt + 4 * hi;
            int j = rowb % 224;
            int bi2 = rowb / 224;
            int ii = bi2 % 224;
            int bb = bi2 / 224;
            #pragma unroll
            for (int nt = 0; nt < 3; nt++) {
                int col = 48 * w + 16 * nt + iq;
                float bv = b2[col];
                float4 vv;
                vv.x = acc2[mt][nt][0] + bv + tbuf[(size_t)(rowb + 0) * 192 + col];
                vv.y = acc2[mt][nt][1] + bv + tbuf[(size_t)(rowb + 1) * 192 + col];
                vv.z = acc2[mt][nt][2] + bv + tbuf[(size_t)(rowb + 2) * 192 + col];
                vv.w = acc2[mt][nt][3] + bv + tbuf[(size_t)(rowb + 3) * 192 + col];
                *(float4*)&outp[(((size_t)bb * 192 + col) * 224 + ii) * 224 + j] = vv;
            }
        }
    }
}

extern "C" void kernel_launch(void* const* d_in, const int* in_sizes, int n_in,
                              void* d_out, int out_size, void* d_ws, size_t ws_size,
                              hipStream_t stream) {
    (void)in_sizes; (void)n_in; (void)out_size; (void)ws_size;
    const float* x    = (const float*)d_in[0];
    const float* pm_w = (const float*)d_in[1];
    const float* pm_b = (const float*)d_in[2];

    char* ws = (char*)d_ws;
    size_t off = 0;
    float* tbuf = (float*)(ws + off); off += (size_t)MROWS * 192 * 4;
    unsigned short* pm_wt = (unsigned short*)(ws + off); off += 192 * 384 * 2;
    unsigned short* wqkv_t[2]; unsigned short* wo_t[2];
    unsigned short* w1_t[2];   unsigned short* w2_t[2];
    for (int s = 0; s < 2; s++) {
        wqkv_t[s] = (unsigned short*)(ws + off); off += 576 * 192 * 2;
        wo_t[s]   = (unsigned short*)(ws + off); off += 192 * 192 * 2;
        w1_t[s]   = (unsigned short*)(ws + off); off += 768 * 192 * 2;
        w2_t[s]   = (unsigned short*)(ws + off); off += 192 * 768 * 2;
    }

    WtArgs wa;
    wa.src[0] = pm_w; wa.dst[0] = pm_wt; wa.K[0] = 384; wa.N[0] = 192;
    for (int s = 0; s < 2; s++) {
        wa.src[1 + 4 * s] = (const float*)d_in[5 + 12 * s];  wa.dst[1 + 4 * s] = wqkv_t[s]; wa.K[1 + 4 * s] = 192; wa.N[1 + 4 * s] = 576;
        wa.src[2 + 4 * s] = (const float*)d_in[7 + 12 * s];  wa.dst[2 + 4 * s] = wo_t[s];   wa.K[2 + 4 * s] = 192; wa.N[2 + 4 * s] = 192;
        wa.src[3 + 4 * s] = (const float*)d_in[11 + 12 * s]; wa.dst[3 + 4 * s] = w1_t[s];   wa.K[3 + 4 * s] = 192; wa.N[3 + 4 * s] = 768;
        wa.src[4 + 4 * s] = (const float*)d_in[13 + 12 * s]; wa.dst[4 + 4 * s] = w2_t[s];   wa.K[4 + 4 * s] = 768; wa.N[4 + 4 * s] = 192;
    }
    wt9_k<<<dim3(576, 9), 256, 0, stream>>>(wa);

    pm_k<<<MROWS / 64, 256, 0, stream>>>(x, pm_wt, pm_b, tbuf);

    for (int s = 0; s < 2; s++) {
        const float* ln1g = (const float*)d_in[3 + 12 * s];
        const float* ln1b = (const float*)d_in[4 + 12 * s];
        const float* pos  = (const float*)d_in[6 + 12 * s];
        const float* bo   = (const float*)d_in[8 + 12 * s];
        const float* ln2g = (const float*)d_in[9 + 12 * s];
        const float* ln2b = (const float*)d_in[10 + 12 * s];
        const float* b1   = (const float*)d_in[12 + 12 * s];
        const float* b2   = (const float*)d_in[14 + 12 * s];

        if (s == 0) {
            attn_blk_k<0><<<2048, 384, 0, stream>>>(wqkv_t[0], wo_t[0], ln1g, ln1b, pos, bo, tbuf);
            mlp_k<0><<<MROWS / 64, 256, 0, stream>>>(w1_t[0], w2_t[0], ln2g, ln2b, b1, b2, tbuf, nullptr);
        } else {
            attn_blk_k<1><<<2048, 384, 0, stream>>>(wqkv_t[1], wo_t[1], ln1g, ln1b, pos, bo, tbuf);
            mlp_k<1><<<MROWS / 64, 256, 0, stream>>>(w1_t[1], w2_t[1], ln2g, ln2b, b1, b2, tbuf, (float*)d_out);
        }
    }
}

// Round 17
// 705.489 us; speedup vs baseline: 1.0496x; 1.0252x over previous
//
#include <hip/hip_runtime.h>
#include <hip/hip_bf16.h>

#define DISPL 3
#define NHEADS 6
#define HH 224
#define NB 2
#define MROWS (NB*HH*HH)   // 100352

typedef __attribute__((ext_vector_type(8))) short short8v;
typedef __attribute__((ext_vector_type(4))) float f32x4;

__device__ __forceinline__ float b2f(unsigned short u) {
    unsigned v = ((unsigned)u) << 16;
    return __builtin_bit_cast(float, v);
}
__device__ __forceinline__ unsigned short f2b(float f) {
    unsigned u = __builtin_bit_cast(unsigned, f);
    return (unsigned short)((u + 0x7FFFu + ((u >> 16) & 1u)) >> 16);
}
__device__ __forceinline__ unsigned pack2(float a, float b) {
    return (unsigned)f2b(a) | ((unsigned)f2b(b) << 16);
}
// sigmoid-form GELU (r16 validated): x*sigmoid(1.702x)
__device__ __forceinline__ float gelu_f(float x) {
    return x / (1.0f + __expf(-1.702f * x));
}

// regroup: build an MFMA A/B fragment (k = 8*hi + e over a 32-wide k-range)
// from C-frag-layout data (k' = 16*m + 4*hi + r).
__device__ __forceinline__ short8v regroup(unsigned pa0, unsigned pa1,
                                           unsigned pb0, unsigned pb1,
                                           int iq, int hi) {
    int l0 = iq + 16 * (2 * (hi & 1));
    int l1 = l0 + 16;
    int msel = hi >> 1;
    unsigned a0 = (unsigned)__shfl((int)pa0, l0), a1 = (unsigned)__shfl((int)pa1, l0);
    unsigned b0 = (unsigned)__shfl((int)pb0, l0), b1 = (unsigned)__shfl((int)pb1, l0);
    unsigned c0 = (unsigned)__shfl((int)pa0, l1), c1 = (unsigned)__shfl((int)pa1, l1);
    unsigned d0 = (unsigned)__shfl((int)pb0, l1), d1 = (unsigned)__shfl((int)pb1, l1);
    unsigned r0 = msel ? b0 : a0, r1 = msel ? b1 : a1;
    unsigned r2 = msel ? d0 : c0, r3 = msel ? d1 : c1;
    short8v out;
    ((unsigned*)&out)[0] = r0; ((unsigned*)&out)[1] = r1;
    ((unsigned*)&out)[2] = r2; ((unsigned*)&out)[3] = r3;
    return out;
}

// ---------------- fused weight convert+transpose for all 9 weights ----------
struct WtArgs {
    const float* src[9];
    unsigned short* dst[9];
    int K[9];
    int N[9];
};
__global__ __launch_bounds__(256) void wt9_k(WtArgs a) {
    int seg = blockIdx.y;
    int K = a.K[seg], N = a.N[seg];
    int idx = blockIdx.x * 256 + threadIdx.x;
    if (idx >= K * N) return;
    int n = idx % N, k = idx / N;
    a.dst[seg][(size_t)n * K + k] = f2b(a.src[seg][idx]);
}

// =====================================================================
// PatchMerge: fused unfold(x) -> X_lds(bf16) -> GEMM(pm_wt) + bias -> tbuf f32
// =====================================================================
__global__ __launch_bounds__(256, 3) void pm_k(const float* __restrict__ x,
                                               const unsigned short* __restrict__ Bt,
                                               const float* __restrict__ bias,
                                               float* __restrict__ tout) {
    __shared__ unsigned short X[64 * 392];
    int t = threadIdx.x, lane = t & 63, w = t >> 6;
    int iq = lane & 15, hi = lane >> 4;
    int m0 = blockIdx.x * 64;
    int lane16 = t & 15, g = t >> 4;
    int base[4];
    #pragma unroll
    for (int rg = 0; rg < 4; rg++) {
        int m = m0 + 16 * rg + lane16;
        int j = m % 224; int bi = m / 224; int i = bi % 224; int b = bi / 224;
        base[rg] = ((b * 96) * 448 + 2 * i) * 448 + 2 * j;
    }
    for (int step = 0; step < 48; step++) {
        int u = g + 16 * step;
        int rg = u & 3, cp = u >> 2;
        int c = cp >> 1, p1 = cp & 1;
        float2 v = *(const float2*)(x + base[rg] + c * 200704 + p1 * 448);
        *(unsigned*)&X[(16 * rg + lane16) * 392 + c * 4 + p1 * 2] = pack2(v.x, v.y);
    }
    __syncthreads();
    f32x4 acc[4][3] = {};
    #pragma unroll 3
    for (int kk = 0; kk < 12; kk++) {
        short8v a[4], bfr[3];
        #pragma unroll
        for (int mt = 0; mt < 4; mt++)
            a[mt] = *(const short8v*)&X[(16 * mt + iq) * 392 + kk * 32 + hi * 8];
        #pragma unroll
        for (int nt = 0; nt < 3; nt++)
            bfr[nt] = *(const short8v*)&Bt[(size_t)(48 * w + 16 * nt + iq) * 384 + kk * 32 + hi * 8];
        #pragma unroll
        for (int mt = 0; mt < 4; mt++)
            #pragma unroll
            for (int nt = 0; nt < 3; nt++)
                acc[mt][nt] = __builtin_amdgcn_mfma_f32_16x16x32_bf16(a[mt], bfr[nt], acc[mt][nt], 0, 0, 0);
    }
    #pragma unroll
    for (int nt = 0; nt < 3; nt++) {
        int col = 48 * w + 16 * nt + iq;
        float bv = bias[col];
        #pragma unroll
        for (int mt = 0; mt < 4; mt++)
            #pragma unroll
            for (int rr = 0; rr < 4; rr++) {
                size_t row = m0 + 16 * mt + 4 * hi + rr;
                tout[row * 192 + col] = acc[mt][nt][rr] + bv;
            }
    }
}

// =====================================================================
// Fused Swin attention block (r16 base). r17: V-pass moved AFTER softmax
// so its weight loads + MFMAs interleave with softmax's serial VALU chain
// (independent work; Vt is wave-private so no barrier change).
// =====================================================================
template<int SHIFT>
__global__ __launch_bounds__(384, 4) void attn_blk_k(
    const unsigned short* __restrict__ wqkvT, const unsigned short* __restrict__ woT,
    const float* __restrict__ ln1g, const float* __restrict__ ln1b,
    const float* __restrict__ pos, const float* __restrict__ bo,
    float* __restrict__ tbuf)
{
    __shared__ unsigned short X[64 * 200];     // reused as AO after QK pass
    __shared__ unsigned short Vt[6][32 * 72];
    __shared__ float Bt49[49 * 52];
    __shared__ int rtb[64];
    unsigned short* AO = &X[0];

    int t = threadIdx.x, lane = t & 63, wid = t >> 6;
    int iq = lane & 15, hi = lane >> 4;
    int window = blockIdx.x;
    int b = window >> 10, wrem = window & 1023;
    int wi = wrem >> 5, wj = wrem & 31;

    auto trow = [&](int p) -> int {
        int pi = p / 7, pj = p - pi * 7;
        int gi = wi * 7 + pi, gj = wj * 7 + pj;
        if (SHIFT) { gi += DISPL; if (gi >= HH) gi -= HH; gj += DISPL; if (gj >= HH) gj -= HH; }
        return (b * HH + gi) * HH + gj;
    };

    if (t < 49) rtb[t] = trow(t);
    for (int e = t; e < 49 * 49; e += 384) {
        int j = e / 49, i = e - 49 * j;
        int ih = i / 7, iw2 = i - ih * 7;
        int jh = j / 7, jw2 = j - jh * 7;
        float v = pos[(jh - ih + 6) * 13 + (jw2 - iw2 + 6)];
        if (SHIFT) {
            bool msk = false;
            if (wi == 31) msk = msk || ((i >= 28) != (j >= 28));
            if (wj == 31) msk = msk || ((iw2 >= 4) != (jw2 >= 4));
            if (msk) v = -1e30f;
        }
        Bt49[j * 52 + i] = v;
    }
    for (int q = t; q < 1500; q += 384) *(unsigned*)&X[49 * 200 + 2 * q] = 0;

    {
        int c8 = t & 7;
        for (int p = t >> 3; p < 49; p += 48) {
            const float* ar = tbuf + (size_t)trow(p) * 192 + c8 * 24;
            float v[24];
            #pragma unroll
            for (int u8 = 0; u8 < 6; u8++) {
                float4 f = *(const float4*)(ar + u8 * 4);
                v[u8 * 4 + 0] = f.x; v[u8 * 4 + 1] = f.y; v[u8 * 4 + 2] = f.z; v[u8 * 4 + 3] = f.w;
            }
            float s = 0.f, sq = 0.f;
            #pragma unroll
            for (int u = 0; u < 24; u++) { s += v[u]; sq += v[u] * v[u]; }
            s += __shfl_xor(s, 1); s += __shfl_xor(s, 2); s += __shfl_xor(s, 4);
            sq += __shfl_xor(sq, 1); sq += __shfl_xor(sq, 2); sq += __shfl_xor(sq, 4);
            float mean = s * (1.f / 192.f);
            float rstd = rsqrtf(sq * (1.f / 192.f) - mean * mean + 1e-5f);
            unsigned short ov[24];
            #pragma unroll
            for (int u8 = 0; u8 < 6; u8++) {
                float4 gg = *(const float4*)(ln1g + c8 * 24 + u8 * 4);
                float4 bb = *(const float4*)(ln1b + c8 * 24 + u8 * 4);
                ov[u8 * 4 + 0] = f2b((v[u8 * 4 + 0] - mean) * rstd * gg.x + bb.x);
                ov[u8 * 4 + 1] = f2b((v[u8 * 4 + 1] - mean) * rstd * gg.y + bb.y);
                ov[u8 * 4 + 2] = f2b((v[u8 * 4 + 2] - mean) * rstd * gg.z + bb.z);
                ov[u8 * 4 + 3] = f2b((v[u8 * 4 + 3] - mean) * rstd * gg.w + bb.w);
            }
            #pragma unroll
            for (int u = 0; u < 3; u++)
                *(short8v*)&X[p * 200 + c8 * 24 + u * 8] = *(short8v*)&ov[u * 8];
        }
    }
    __syncthreads();

    int hq = wid * 32;
    unsigned short* vt = &Vt[wid][0];

    // ---- Q,K pass ----
    short8v bQ[4], aK[4];
    {
        f32x4 dq[2][4] = {}, dk[2][4] = {};
        #pragma unroll
        for (int kk = 0; kk < 6; kk++) {
            short8v aq[2], ak[2], bx[4];
            #pragma unroll
            for (int s2 = 0; s2 < 2; s2++) {
                aq[s2] = *(const short8v*)&wqkvT[(size_t)(hq + 16 * s2 + iq) * 192 + kk * 32 + hi * 8];
                ak[s2] = *(const short8v*)&wqkvT[(size_t)(192 + hq + 16 * s2 + iq) * 192 + kk * 32 + hi * 8];
            }
            #pragma unroll
            for (int tg = 0; tg < 4; tg++)
                bx[tg] = *(const short8v*)&X[(16 * tg + iq) * 200 + kk * 32 + hi * 8];
            #pragma unroll
            for (int s2 = 0; s2 < 2; s2++)
                #pragma unroll
                for (int tg = 0; tg < 4; tg++) {
                    dq[s2][tg] = __builtin_amdgcn_mfma_f32_16x16x32_bf16(aq[s2], bx[tg], dq[s2][tg], 0, 0, 0);
                    dk[s2][tg] = __builtin_amdgcn_mfma_f32_16x16x32_bf16(ak[s2], bx[tg], dk[s2][tg], 0, 0, 0);
                }
        }
        #pragma unroll
        for (int tg = 0; tg < 4; tg++) {
            unsigned q00 = pack2(dq[0][tg][0], dq[0][tg][1]), q01 = pack2(dq[0][tg][2], dq[0][tg][3]);
            unsigned q10 = pack2(dq[1][tg][0], dq[1][tg][1]), q11 = pack2(dq[1][tg][2], dq[1][tg][3]);
            bQ[tg] = regroup(q00, q01, q10, q11, iq, hi);
            unsigned k00 = pack2(dk[0][tg][0], dk[0][tg][1]), k01 = pack2(dk[0][tg][2], dk[0][tg][3]);
            unsigned k10 = pack2(dk[1][tg][0], dk[1][tg][1]), k11 = pack2(dk[1][tg][2], dk[1][tg][3]);
            aK[tg] = regroup(k00, k01, k10, k11, iq, hi);
        }
    }

    f32x4 st[4][4] = {};
    #pragma unroll
    for (int jt = 0; jt < 4; jt++)
        #pragma unroll
        for (int it = 0; it < 4; it++)
            st[jt][it] = __builtin_amdgcn_mfma_f32_16x16x32_bf16(aK[jt], bQ[it], st[jt][it], 0, 0, 0);

    const float scale = 0.17677669529663687f;
    unsigned pkp[4][4][2];
    #pragma unroll
    for (int it = 0; it < 4; it++) {
        int i = iq + 16 * it;
        int icl = i > 48 ? 48 : i;
        float sv[16];
        #pragma unroll
        for (int jt = 0; jt < 4; jt++) {
            #pragma unroll
            for (int r = 0; r < 4; r++) {
                int jj = 16 * jt + 4 * hi + r;
                float s;
                if (jj < 49) s = st[jt][it][r] * scale + Bt49[jj * 52 + icl];
                else s = -1e30f;
                sv[jt * 4 + r] = s;
            }
        }
        float mx = sv[0];
        #pragma unroll
        for (int u = 1; u < 16; u++) mx = fmaxf(mx, sv[u]);
        mx = fmaxf(mx, __shfl_xor(mx, 16));
        mx = fmaxf(mx, __shfl_xor(mx, 32));
        float sum = 0.f;
        #pragma unroll
        for (int u = 0; u < 16; u++) { sv[u] = __expf(sv[u] - mx); sum += sv[u]; }
        sum += __shfl_xor(sum, 16);
        sum += __shfl_xor(sum, 32);
        float rinv = 1.0f / sum;
        #pragma unroll
        for (int jt = 0; jt < 4; jt++) {
            pkp[it][jt][0] = pack2(sv[jt * 4 + 0] * rinv, sv[jt * 4 + 1] * rinv);
            pkp[it][jt][1] = pack2(sv[jt * 4 + 2] * rinv, sv[jt * 4 + 3] * rinv);
        }
    }

    // ---- V pass (moved here: independent of softmax; interleaves with it) ----
    {
        f32x4 dv[2][4] = {};
        #pragma unroll
        for (int kk = 0; kk < 6; kk++) {
            short8v aw[2], bx[4];
            #pragma unroll
            for (int s2 = 0; s2 < 2; s2++)
                aw[s2] = *(const short8v*)&wqkvT[(size_t)(384 + hq + 16 * s2 + iq) * 192 + kk * 32 + hi * 8];
            #pragma unroll
            for (int tg = 0; tg < 4; tg++)
                bx[tg] = *(const short8v*)&X[(16 * tg + iq) * 200 + kk * 32 + hi * 8];
            #pragma unroll
            for (int s2 = 0; s2 < 2; s2++)
                #pragma unroll
                for (int tg = 0; tg < 4; tg++)
                    dv[s2][tg] = __builtin_amdgcn_mfma_f32_16x16x32_bf16(aw[s2], bx[tg], dv[s2][tg], 0, 0, 0);
        }
        #pragma unroll
        for (int s2 = 0; s2 < 2; s2++)
            #pragma unroll
            for (int tg = 0; tg < 4; tg++)
                #pragma unroll
                for (int rr = 0; rr < 4; rr++)
                    vt[(16 * s2 + 4 * hi + rr) * 72 + 16 * tg + iq] = f2b(dv[s2][tg][rr]);
    }

    f32x4 o[4][2] = {};
    #pragma unroll
    for (int kk = 0; kk < 2; kk++) {
        short8v bV[2];
        #pragma unroll
        for (int ntv = 0; ntv < 2; ntv++)
            bV[ntv] = *(const short8v*)&vt[(iq + 16 * ntv) * 72 + kk * 32 + hi * 8];
        #pragma unroll
        for (int it = 0; it < 4; it++) {
            short8v aP = regroup(pkp[it][2 * kk][0], pkp[it][2 * kk][1],
                                 pkp[it][2 * kk + 1][0], pkp[it][2 * kk + 1][1], iq, hi);
            o[it][0] = __builtin_amdgcn_mfma_f32_16x16x32_bf16(aP, bV[0], o[it][0], 0, 0, 0);
            o[it][1] = __builtin_amdgcn_mfma_f32_16x16x32_bf16(aP, bV[1], o[it][1], 0, 0, 0);
        }
    }

    __syncthreads();
    #pragma unroll
    for (int it = 0; it < 4; it++)
        #pragma unroll
        for (int ntv = 0; ntv < 2; ntv++)
            #pragma unroll
            for (int rr = 0; rr < 4; rr++)
                AO[(16 * it + 4 * hi + rr) * 200 + hq + 16 * ntv + iq] = f2b(o[it][ntv][rr]);
    __syncthreads();

    f32x4 a2[4][2] = {};
    #pragma unroll
    for (int kk = 0; kk < 6; kk++) {
        short8v aA[4], bW[2];
        #pragma unroll
        for (int mt = 0; mt < 4; mt++)
            aA[mt] = *(const short8v*)&AO[(16 * mt + iq) * 200 + kk * 32 + hi * 8];
        #pragma unroll
        for (int nt = 0; nt < 2; nt++)
            bW[nt] = *(const short8v*)&woT[(size_t)(32 * wid + 16 * nt + iq) * 192 + kk * 32 + hi * 8];
        #pragma unroll
        for (int mt = 0; mt < 4; mt++)
            #pragma unroll
            for (int nt = 0; nt < 2; nt++)
                a2[mt][nt] = __builtin_amdgcn_mfma_f32_16x16x32_bf16(aA[mt], bW[nt], a2[mt][nt], 0, 0, 0);
    }
    #pragma unroll
    for (int nt = 0; nt < 2; nt++) {
        int col = 32 * wid + 16 * nt + iq;
        float bv = bo[col];
        #pragma unroll
        for (int mt = 0; mt < 4; mt++)
            #pragma unroll
            for (int rr = 0; rr < 4; rr++) {
                int i = 16 * mt + 4 * hi + rr;
                if (i < 49) {
                    size_t r = (size_t)rtb[i] * 192 + col;
                    tbuf[r] = a2[mt][nt][rr] + bv + tbuf[r];
                }
            }
    }
}

// =====================================================================
// Fused MLP block v6 + TO (r15/r16 proven): TO=0 -> tbuf; TO=1 -> d_out
// in [b][c][i][j] layout (tr_k fused). sigmoid-GELU.
// =====================================================================
template<int TO>
__global__ __launch_bounds__(256, 3) void mlp_k(const unsigned short* __restrict__ w1T,
                                                const unsigned short* __restrict__ w2T,
                                                const float* __restrict__ ln2g,
                                                const float* __restrict__ ln2b,
                                                const float* __restrict__ b1,
                                                const float* __restrict__ b2,
                                                float* __restrict__ tbuf,
                                                float* __restrict__ outp)
{
    __shared__ unsigned short X[64 * 200];
    __shared__ unsigned short Hl[64 * 200];
    int t = threadIdx.x, lane = t & 63, w = t >> 6;
    int iq = lane & 15, hi = lane >> 4;
    int m0 = blockIdx.x * 64;

    {
        int c8 = t & 7, p0 = t >> 3;
        #pragma unroll
        for (int pp = 0; pp < 2; pp++) {
            int p = p0 + 32 * pp;
            const float* ar = tbuf + (size_t)(m0 + p) * 192 + c8 * 24;
            float v[24];
            #pragma unroll
            for (int u8 = 0; u8 < 6; u8++) {
                float4 f = *(const float4*)(ar + u8 * 4);
                v[u8 * 4 + 0] = f.x; v[u8 * 4 + 1] = f.y; v[u8 * 4 + 2] = f.z; v[u8 * 4 + 3] = f.w;
            }
            float s = 0.f, sq = 0.f;
            #pragma unroll
            for (int u = 0; u < 24; u++) { s += v[u]; sq += v[u] * v[u]; }
            s += __shfl_xor(s, 1); s += __shfl_xor(s, 2); s += __shfl_xor(s, 4);
            sq += __shfl_xor(sq, 1); sq += __shfl_xor(sq, 2); sq += __shfl_xor(sq, 4);
            float mean = s * (1.f / 192.f);
            float rstd = rsqrtf(sq * (1.f / 192.f) - mean * mean + 1e-5f);
            unsigned short ov[24];
            #pragma unroll
            for (int u8 = 0; u8 < 6; u8++) {
                float4 gg = *(const float4*)(ln2g + c8 * 24 + u8 * 4);
                float4 bb = *(const float4*)(ln2b + c8 * 24 + u8 * 4);
                ov[u8 * 4 + 0] = f2b((v[u8 * 4 + 0] - mean) * rstd * gg.x + bb.x);
                ov[u8 * 4 + 1] = f2b((v[u8 * 4 + 1] - mean) * rstd * gg.y + bb.y);
                ov[u8 * 4 + 2] = f2b((v[u8 * 4 + 2] - mean) * rstd * gg.z + bb.z);
                ov[u8 * 4 + 3] = f2b((v[u8 * 4 + 3] - mean) * rstd * gg.w + bb.w);
            }
            #pragma unroll
            for (int u = 0; u < 3; u++)
                *(short8v*)&X[p * 200 + c8 * 24 + u * 8] = *(short8v*)&ov[u * 8];
        }
    }
    __syncthreads();

    f32x4 acc2[4][3] = {};
    #pragma unroll 1
    for (int c = 0; c < 4; c++) {
        f32x4 acc1[4][3] = {};
        #pragma unroll
        for (int kk = 0; kk < 6; kk++) {
            short8v aX[4], bW[3];
            #pragma unroll
            for (int mt = 0; mt < 4; mt++)
                aX[mt] = *(const short8v*)&X[(16 * mt + iq) * 200 + kk * 32 + hi * 8];
            #pragma unroll
            for (int nt = 0; nt < 3; nt++)
                bW[nt] = *(const short8v*)&w1T[(size_t)(c * 192 + 48 * w + 16 * nt + iq) * 192 + kk * 32 + hi * 8];
            #pragma unroll
            for (int mt = 0; mt < 4; mt++)
                #pragma unroll
                for (int nt = 0; nt < 3; nt++)
                    acc1[mt][nt] = __builtin_amdgcn_mfma_f32_16x16x32_bf16(aX[mt], bW[nt], acc1[mt][nt], 0, 0, 0);
        }
        #pragma unroll
        for (int nt = 0; nt < 3; nt++) {
            int col = 48 * w + 16 * nt + iq;
            float bv = b1[c * 192 + col];
            #pragma unroll
            for (int mt = 0; mt < 4; mt++)
                #pragma unroll
                for (int rr = 0; rr < 4; rr++)
                    Hl[(16 * mt + 4 * hi + rr) * 200 + col] = f2b(gelu_f(acc1[mt][nt][rr] + bv));
        }
        __syncthreads();
        #pragma unroll
        for (int kk = 0; kk < 6; kk++) {
            short8v aH[4], bW[3];
            #pragma unroll
            for (int mt = 0; mt < 4; mt++)
                aH[mt] = *(const short8v*)&Hl[(16 * mt + iq) * 200 + kk * 32 + hi * 8];
            #pragma unroll
            for (int nt = 0; nt < 3; nt++)
                bW[nt] = *(const short8v*)&w2T[(size_t)(48 * w + 16 * nt + iq) * 768 + c * 192 + kk * 32 + hi * 8];
            #pragma unroll
            for (int mt = 0; mt < 4; mt++)
                #pragma unroll
                for (int nt = 0; nt < 3; nt++)
                    acc2[mt][nt] = __builtin_amdgcn_mfma_f32_16x16x32_bf16(aH[mt], bW[nt], acc2[mt][nt], 0, 0, 0);
        }
        __syncthreads();
    }
    if (TO == 0) {
        #pragma unroll
        for (int nt = 0; nt < 3; nt++) {
            int col = 48 * w + 16 * nt + iq;
            float bv = b2[col];
            #pragma unroll
            for (int mt = 0; mt < 4; mt++)
                #pragma unroll
                for (int rr = 0; rr < 4; rr++) {
                    size_t r = (size_t)(m0 + 16 * mt + 4 * hi + rr) * 192 + col;
                    tbuf[r] = acc2[mt][nt][rr] + bv + tbuf[r];
                }
        }
    } else {
        #pragma unroll
        for (int mt = 0; mt < 4; mt++) {
            int rowb = m0 + 16 * mt + 4 * hi;
            int j = rowb % 224;
            int bi2 = rowb / 224;
            int ii = bi2 % 224;
            int bb = bi2 / 224;
            #pragma unroll
            for (int nt = 0; nt < 3; nt++) {
                int col = 48 * w + 16 * nt + iq;
                float bv = b2[col];
                float4 vv;
                vv.x = acc2[mt][nt][0] + bv + tbuf[(size_t)(rowb + 0) * 192 + col];
                vv.y = acc2[mt][nt][1] + bv + tbuf[(size_t)(rowb + 1) * 192 + col];
                vv.z = acc2[mt][nt][2] + bv + tbuf[(size_t)(rowb + 2) * 192 + col];
                vv.w = acc2[mt][nt][3] + bv + tbuf[(size_t)(rowb + 3) * 192 + col];
                *(float4*)&outp[(((size_t)bb * 192 + col) * 224 + ii) * 224 + j] = vv;
            }
        }
    }
}

extern "C" void kernel_launch(void* const* d_in, const int* in_sizes, int n_in,
                              void* d_out, int out_size, void* d_ws, size_t ws_size,
                              hipStream_t stream) {
    (void)in_sizes; (void)n_in; (void)out_size; (void)ws_size;
    const float* x    = (const float*)d_in[0];
    const float* pm_w = (const float*)d_in[1];
    const float* pm_b = (const float*)d_in[2];

    char* ws = (char*)d_ws;
    size_t off = 0;
    float* tbuf = (float*)(ws + off); off += (size_t)MROWS * 192 * 4;
    unsigned short* pm_wt = (unsigned short*)(ws + off); off += 192 * 384 * 2;
    unsigned short* wqkv_t[2]; unsigned short* wo_t[2];
    unsigned short* w1_t[2];   unsigned short* w2_t[2];
    for (int s = 0; s < 2; s++) {
        wqkv_t[s] = (unsigned short*)(ws + off); off += 576 * 192 * 2;
        wo_t[s]   = (unsigned short*)(ws + off); off += 192 * 192 * 2;
        w1_t[s]   = (unsigned short*)(ws + off); off += 768 * 192 * 2;
        w2_t[s]   = (unsigned short*)(ws + off); off += 192 * 768 * 2;
    }

    WtArgs wa;
    wa.src[0] = pm_w; wa.dst[0] = pm_wt; wa.K[0] = 384; wa.N[0] = 192;
    for (int s = 0; s < 2; s++) {
        wa.src[1 + 4 * s] = (const float*)d_in[5 + 12 * s];  wa.dst[1 + 4 * s] = wqkv_t[s]; wa.K[1 + 4 * s] = 192; wa.N[1 + 4 * s] = 576;
        wa.src[2 + 4 * s] = (const float*)d_in[7 + 12 * s];  wa.dst[2 + 4 * s] = wo_t[s];   wa.K[2 + 4 * s] = 192; wa.N[2 + 4 * s] = 192;
        wa.src[3 + 4 * s] = (const float*)d_in[11 + 12 * s]; wa.dst[3 + 4 * s] = w1_t[s];   wa.K[3 + 4 * s] = 192; wa.N[3 + 4 * s] = 768;
        wa.src[4 + 4 * s] = (const float*)d_in[13 + 12 * s]; wa.dst[4 + 4 * s] = w2_t[s];   wa.K[4 + 4 * s] = 768; wa.N[4 + 4 * s] = 192;
    }
    wt9_k<<<dim3(576, 9), 256, 0, stream>>>(wa);

    pm_k<<<MROWS / 64, 256, 0, stream>>>(x, pm_wt, pm_b, tbuf);

    for (int s = 0; s < 2; s++) {
        const float* ln1g = (const float*)d_in[3 + 12 * s];
        const float* ln1b = (const float*)d_in[4 + 12 * s];
        const float* pos  = (const float*)d_in[6 + 12 * s];
        const float* bo   = (const float*)d_in[8 + 12 * s];
        const float* ln2g = (const float*)d_in[9 + 12 * s];
        const float* ln2b = (const float*)d_in[10 + 12 * s];
        const float* b1   = (const float*)d_in[12 + 12 * s];
        const float* b2   = (const float*)d_in[14 + 12 * s];

        if (s == 0) {
            attn_blk_k<0><<<2048, 384, 0, stream>>>(wqkv_t[0], wo_t[0], ln1g, ln1b, pos, bo, tbuf);
            mlp_k<0><<<MROWS / 64, 256, 0, stream>>>(w1_t[0], w2_t[0], ln2g, ln2b, b1, b2, tbuf, nullptr);
        } else {
            attn_blk_k<1><<<2048, 384, 0, stream>>>(wqkv_t[1], wo_t[1], ln1g, ln1b, pos, bo, tbuf);
            mlp_k<1><<<MROWS / 64, 256, 0, stream>>>(w1_t[1], w2_t[1], ln2g, ln2b, b1, b2, tbuf, (float*)d_out);
        }
    }
}